// Round 2
// baseline (801.237 us; speedup 1.0000x reference)
//
#include <hip/hip_runtime.h>
#include <hip/hip_bf16.h>

// Problem constants (GroupedQueryAttention): B=2, T=2048, HID=2048, H=16, HKV=4, HD=128
#define B_   2
#define T_   2048
#define HID_ 2048
#define H_   16
#define HKV_ 4
#define HD_  128
#define NQKV 3072   // H*HD + 2*HKV*HD = 2048 + 512 + 512
#define M_   4096   // B*T
#define SCALE_ 0.08838834764831845f  // 128^-0.5

using f32x4 = __attribute__((ext_vector_type(4))) float;
using s16x8 = __attribute__((ext_vector_type(8))) short;

typedef const __attribute__((address_space(1))) unsigned int* gptr_t;
typedef __attribute__((address_space(3))) unsigned int* lptr_t;

__device__ __forceinline__ unsigned short f2bf(float f) {
  __hip_bfloat16 h = __float2bfloat16(f);
  return *reinterpret_cast<unsigned short*>(&h);
}
__device__ __forceinline__ float bf2f(unsigned short u) {
  union { unsigned int u; float f; } x;
  x.u = ((unsigned int)u) << 16;
  return x.f;
}

// ---------------- elementwise cast f32 -> bf16 (vectorized) ----------------
__global__ void cast_bf16_k(const float* __restrict__ in, unsigned short* __restrict__ out, int n4) {
  int i = blockIdx.x * 256 + threadIdx.x;
  if (i >= n4) return;
  float4 v = ((const float4*)in)[i];
  ushort4 o;
  o.x = f2bf(v.x); o.y = f2bf(v.y); o.z = f2bf(v.z); o.w = f2bf(v.w);
  ((ushort4*)out)[i] = o;
}

// ---------------- tiled transpose-cast: in [R][C] f32 -> out [C][R] bf16 ----------------
__global__ void transpose_cast_k(const float* __restrict__ in, unsigned short* __restrict__ out,
                                 int R, int C) {
  __shared__ float tile[32][33];
  const int tc = blockIdx.x * 32, tr = blockIdx.y * 32;
  const int lx = threadIdx.x & 31, ly = threadIdx.x >> 5;
#pragma unroll
  for (int i = 0; i < 32; i += 8) tile[ly + i][lx] = in[(long)(tr + ly + i) * C + tc + lx];
  __syncthreads();
#pragma unroll
  for (int i = 0; i < 32; i += 8)
    out[(long)(tc + ly + i) * R + tr + lx] = f2bf(tile[lx][ly + i]);
}

// ---------------- V transpose (bf16): QKV cols [2560..3071] -> Vt[b*512+n][t] ----------------
__global__ void transpose_v_k(const unsigned short* __restrict__ qkv, unsigned short* __restrict__ vtp) {
  __shared__ unsigned short tile[32][33];
  const int b = blockIdx.z;
  const int t0 = blockIdx.x * 32, n0 = blockIdx.y * 32;
  const int lx = threadIdx.x & 31, ly = threadIdx.x >> 5;
#pragma unroll
  for (int i = 0; i < 32; i += 8)
    tile[ly + i][lx] = qkv[(long)(b * T_ + t0 + ly + i) * NQKV + 2560 + n0 + lx];
  __syncthreads();
#pragma unroll
  for (int i = 0; i < 32; i += 8)
    vtp[(long)(b * 512 + n0 + ly + i) * T_ + t0 + lx] = tile[lx][ly + i];
}

// ---------------- RoPE tables: cos/sin [T][64] ----------------
__global__ void rope_table_k(float* __restrict__ cosT, float* __restrict__ sinT) {
  int idx = blockIdx.x * 256 + threadIdx.x;  // t*64 + i
  int tt = idx >> 6, i = idx & 63;
  float inv = powf(10000.0f, -(float)i * (1.0f / 64.0f));
  float ang = (float)tt * inv;
  cosT[idx] = cosf(ang);
  sinT[idx] = sinf(ang);
}

// ---------------- RoPE apply in-place on QKV (Q heads get *SCALE folded in) ----------------
__global__ void rope_apply_k(unsigned short* __restrict__ qkv,
                             const float* __restrict__ cosT, const float* __restrict__ sinT) {
  int idx = blockIdx.x * 256 + threadIdx.x;  // [0, M_*20*64)
  int i = idx & 63;
  int r = idx >> 6;
  int hh = r % 20;          // 0..15 = Q heads, 16..19 = K heads
  int m = r / 20;           // row in [0, M_)
  int tt = m & (T_ - 1);
  int col = (hh < 16) ? hh * 128 + i : 2048 + (hh - 16) * 128 + i;
  float scl = (hh < 16) ? SCALE_ : 1.0f;
  unsigned short* p = qkv + (long)m * NQKV + col;
  float x0 = bf2f(p[0]), x1 = bf2f(p[64]);
  float c = cosT[tt * 64 + i], s = sinT[tt * 64 + i];
  p[0]  = f2bf((x0 * c - x1 * s) * scl);
  p[64] = f2bf((x1 * c + x0 * s) * scl);
}

// ---------------- bf16 GEMM, B transposed: C[M][N] = A[M][K] * Bt[N][K]^T ----------------
// m97 structure: 128x128 tile, 4 waves (each 64x64 = 4x4 frags of 16x16x32), BK=32,
// global_load_lds width 16 for staging.
template <bool BF16OUT>
__global__ __launch_bounds__(256) void gemm_bt(const short* __restrict__ A, const short* __restrict__ Bt,
                                               void* __restrict__ Cv, int M, int N, int K) {
  __shared__ short lA[4096];  // [128][32]
  __shared__ short lB[4096];  // [128][32]
  const int t = threadIdx.x;
  const int l = t & 63;
  const int w = t >> 6;
  const int wr = (w >> 1) * 64, wc = (w & 1) * 64;
  const int lr = l & 15, lk = (l >> 4) * 8;

  const short* Ag = A + (long)(blockIdx.x * 128 + (t >> 2)) * K + (t & 3) * 8;
  const short* Bg = Bt + (long)(blockIdx.y * 128 + (t >> 2)) * K + (t & 3) * 8;

  f32x4 acc[4][4] = {};

  for (int k0 = 0; k0 < K; k0 += 32) {
    __builtin_amdgcn_global_load_lds((gptr_t)(Ag + k0),               (lptr_t)&lA[t * 8],        16, 0, 0);
    __builtin_amdgcn_global_load_lds((gptr_t)(Ag + (long)64 * K + k0), (lptr_t)&lA[2048 + t * 8], 16, 0, 0);
    __builtin_amdgcn_global_load_lds((gptr_t)(Bg + k0),               (lptr_t)&lB[t * 8],        16, 0, 0);
    __builtin_amdgcn_global_load_lds((gptr_t)(Bg + (long)64 * K + k0), (lptr_t)&lB[2048 + t * 8], 16, 0, 0);
    __syncthreads();
    s16x8 af[4], bfr[4];
#pragma unroll
    for (int m = 0; m < 4; ++m) af[m] = *(const s16x8*)&lA[(wr + m * 16 + lr) * 32 + lk];
#pragma unroll
    for (int n = 0; n < 4; ++n) bfr[n] = *(const s16x8*)&lB[(wc + n * 16 + lr) * 32 + lk];
#pragma unroll
    for (int m = 0; m < 4; ++m)
#pragma unroll
      for (int n = 0; n < 4; ++n)
        acc[m][n] = __builtin_amdgcn_mfma_f32_16x16x32_bf16(af[m], bfr[n], acc[m][n], 0, 0, 0);
    __syncthreads();
  }

#pragma unroll
  for (int m = 0; m < 4; ++m) {
    const int row0 = blockIdx.x * 128 + wr + m * 16 + (l >> 4) * 4;
#pragma unroll
    for (int n = 0; n < 4; ++n) {
      const int col = blockIdx.y * 128 + wc + n * 16 + lr;
#pragma unroll
      for (int r = 0; r < 4; ++r) {
        float v = acc[m][n][r];
        if constexpr (BF16OUT)
          ((unsigned short*)Cv)[(long)(row0 + r) * N + col] = f2bf(v);
        else
          ((float*)Cv)[(long)(row0 + r) * N + col] = v;
      }
    }
  }
}

// ---------------- causal GQA flash attention ----------------
// grid (qi=32, bh=32). Block: 256 thr = 4 waves; each wave owns 16 q-rows.
// K/V fragments read directly from global (L2-resident: 512KB per (b,hkv)).
// S/P layout per 16x16x32 MFMA: C row=(l>>4)*4+r, col=l&15; A row=l&15.
__global__ __launch_bounds__(256) void attn_kernel(const short* __restrict__ qkv,
                                                   const short* __restrict__ vt,
                                                   unsigned short* __restrict__ outp) {
  const int qi = blockIdx.x;
  const int bh = blockIdx.y;
  const int b = bh >> 4, h = bh & 15, hkv = h >> 2;
  const int t = threadIdx.x, w = t >> 6, l = t & 63;
  const int lr = l & 15, lg = l >> 4;

  __shared__ short lP[4][16 * 72];  // per-wave P tile [16 q][64 kv], padded ld=72

  // Q fragments (A operand): row = lr, k contiguous. Scale already folded in by RoPE.
  const short* qp = qkv + (long)(b * T_ + qi * 64 + w * 16 + lr) * NQKV + h * HD_;
  s16x8 qf[4];
#pragma unroll
  for (int ks = 0; ks < 4; ++ks) qf[ks] = *(const s16x8*)(qp + ks * 32 + lg * 8);

  const short* kb = qkv + (long)(b * T_) * NQKV + 2048 + hkv * HD_;
  const short* vb = vt + (long)(b * 512 + hkv * HD_) * T_;

  f32x4 o[8] = {};
  float mrun[4], lrun[4];
#pragma unroll
  for (int r = 0; r < 4; ++r) { mrun[r] = -1e30f; lrun[r] = 0.f; }

  short* pw = &lP[w][0];

  for (int kvt = 0; kvt <= qi; ++kvt) {
    // ---- S = Q K^T (16 q x 64 kv per wave) ----
    f32x4 s[4] = {};
#pragma unroll
    for (int nb = 0; nb < 4; ++nb) {
      const short* kr = kb + (long)(kvt * 64 + nb * 16 + lr) * NQKV;
#pragma unroll
      for (int ks = 0; ks < 4; ++ks) {
        s16x8 kf = *(const s16x8*)(kr + ks * 32 + lg * 8);
        s[nb] = __builtin_amdgcn_mfma_f32_16x16x32_bf16(qf[ks], kf, s[nb], 0, 0, 0);
      }
    }
    // ---- causal mask on the diagonal tile ----
    if (kvt == qi) {
#pragma unroll
      for (int nb = 0; nb < 4; ++nb)
#pragma unroll
        for (int r = 0; r < 4; ++r)
          if (nb * 16 + lr > w * 16 + lg * 4 + r) s[nb][r] = -1e30f;
    }
    // ---- online softmax (rows live in 16-lane groups) ----
    float sc[4];
#pragma unroll
    for (int r = 0; r < 4; ++r) {
      float v = fmaxf(fmaxf(s[0][r], s[1][r]), fmaxf(s[2][r], s[3][r]));
      v = fmaxf(v, __shfl_xor(v, 1));
      v = fmaxf(v, __shfl_xor(v, 2));
      v = fmaxf(v, __shfl_xor(v, 4));
      v = fmaxf(v, __shfl_xor(v, 8));
      float mnew = fmaxf(mrun[r], v);
      sc[r] = __expf(mrun[r] - mnew);
      mrun[r] = mnew;
    }
    float ps[4] = {0.f, 0.f, 0.f, 0.f};
#pragma unroll
    for (int nb = 0; nb < 4; ++nb)
#pragma unroll
      for (int r = 0; r < 4; ++r) {
        float p = __expf(s[nb][r] - mrun[r]);
        s[nb][r] = p;
        ps[r] += p;
      }
#pragma unroll
    for (int r = 0; r < 4; ++r) {
      ps[r] += __shfl_xor(ps[r], 1);
      ps[r] += __shfl_xor(ps[r], 2);
      ps[r] += __shfl_xor(ps[r], 4);
      ps[r] += __shfl_xor(ps[r], 8);
      lrun[r] = lrun[r] * sc[r] + ps[r];
    }
#pragma unroll
    for (int db = 0; db < 8; ++db)
#pragma unroll
      for (int r = 0; r < 4; ++r) o[db][r] *= sc[r];
    // ---- P -> LDS (bf16), C-layout rows -> A-layout rows ----
#pragma unroll
    for (int nb = 0; nb < 4; ++nb)
#pragma unroll
      for (int r = 0; r < 4; ++r)
        pw[(lg * 4 + r) * 72 + nb * 16 + lr] = (short)f2bf(s[nb][r]);
    // ---- O += P V  (B operand from pre-transposed Vt: row=d, k=kv contiguous) ----
#pragma unroll
    for (int ks2 = 0; ks2 < 2; ++ks2) {
      s16x8 pf = *(const s16x8*)&pw[lr * 72 + ks2 * 32 + lg * 8];
#pragma unroll
      for (int db = 0; db < 8; ++db) {
        s16x8 vf = *(const s16x8*)(vb + (long)(db * 16 + lr) * T_ + kvt * 64 + ks2 * 32 + lg * 8);
        o[db] = __builtin_amdgcn_mfma_f32_16x16x32_bf16(pf, vf, o[db], 0, 0, 0);
      }
    }
  }
  // ---- normalize and store (bf16) ----
  unsigned short* ob = outp + (long)(b * T_ + qi * 64 + w * 16) * HID_ + h * HD_;
#pragma unroll
  for (int db = 0; db < 8; ++db)
#pragma unroll
    for (int r = 0; r < 4; ++r)
      ob[(long)(lg * 4 + r) * HID_ + db * 16 + lr] = f2bf(o[db][r] / lrun[r]);
}

// ---------------- launch ----------------
extern "C" void kernel_launch(void* const* d_in, const int* in_sizes, int n_in,
                              void* d_out, int out_size, void* d_ws, size_t ws_size,
                              hipStream_t stream) {
  (void)in_sizes; (void)n_in; (void)out_size; (void)ws_size;
  const float* x  = (const float*)d_in[0];
  const float* Wq = (const float*)d_in[1];
  const float* Wk = (const float*)d_in[2];
  const float* Wv = (const float*)d_in[3];
  const float* Wo = (const float*)d_in[4];
  float* outp = (float*)d_out;

  char* wsp = (char*)d_ws;
  auto take = [&](size_t bytes) { char* p = wsp; wsp += (bytes + 255) & ~(size_t)255; return p; };
  unsigned short* xb    = (unsigned short*)take((size_t)M_ * HID_ * 2);    // x in bf16
  unsigned short* WqkvT = (unsigned short*)take((size_t)NQKV * HID_ * 2);  // [3072][2048] W^T bf16
  unsigned short* WoT   = (unsigned short*)take((size_t)HID_ * HID_ * 2);  // [2048][2048]
  unsigned short* QKV   = (unsigned short*)take((size_t)M_ * NQKV * 2);    // [4096][3072]
  unsigned short* Vtb   = (unsigned short*)take((size_t)1024 * T_ * 2);    // [b*512+n][T]
  unsigned short* AO    = (unsigned short*)take((size_t)M_ * HID_ * 2);    // attention out bf16
  float* cosT = (float*)take((size_t)T_ * 64 * 4);
  float* sinT = (float*)take((size_t)T_ * 64 * 4);

  cast_bf16_k<<<8192, 256, 0, stream>>>(x, xb, M_ * HID_ / 4);
  transpose_cast_k<<<dim3(64, 64), 256, 0, stream>>>(Wq, WqkvT, 2048, 2048);
  transpose_cast_k<<<dim3(16, 64), 256, 0, stream>>>(Wk, WqkvT + (size_t)2048 * 2048, 2048, 512);
  transpose_cast_k<<<dim3(16, 64), 256, 0, stream>>>(Wv, WqkvT + (size_t)2560 * 2048, 2048, 512);
  transpose_cast_k<<<dim3(64, 64), 256, 0, stream>>>(Wo, WoT, 2048, 2048);
  rope_table_k<<<512, 256, 0, stream>>>(cosT, sinT);

  // QKV = xb @ WqkvT^T   (M=4096, N=3072, K=2048), bf16 out
  gemm_bt<true><<<dim3(32, 24), 256, 0, stream>>>((const short*)xb, (const short*)WqkvT,
                                                  (void*)QKV, M_, NQKV, HID_);
  rope_apply_k<<<(M_ * 20 * 64) / 256, 256, 0, stream>>>(QKV, cosT, sinT);
  transpose_v_k<<<dim3(64, 16, 2), 256, 0, stream>>>(QKV, Vtb);

  attn_kernel<<<dim3(32, 32), 256, 0, stream>>>((const short*)QKV, (const short*)Vtb, AO);

  // out = AO @ WoT^T   (M=4096, N=2048, K=2048), f32 out
  gemm_bt<false><<<dim3(32, 16), 256, 0, stream>>>((const short*)AO, (const short*)WoT,
                                                   (void*)outp, M_, HID_, HID_);
}

// Round 5
// 409.727 us; speedup vs baseline: 1.9555x; 1.9555x over previous
//
#include <hip/hip_runtime.h>
#include <hip/hip_bf16.h>

// Problem constants (GroupedQueryAttention): B=2, T=2048, HID=2048, H=16, HKV=4, HD=128
#define B_   2
#define T_   2048
#define HID_ 2048
#define H_   16
#define HKV_ 4
#define HD_  128
#define NQKV 3072   // H*HD + 2*HKV*HD = 2048 + 512 + 512
#define M_   4096   // B*T
#define SCALE_ 0.08838834764831845f  // 128^-0.5

using f32x4 = __attribute__((ext_vector_type(4))) float;
using s16x8 = __attribute__((ext_vector_type(8))) short;

typedef const __attribute__((address_space(1))) unsigned int* gptr_t;
typedef __attribute__((address_space(3))) unsigned int* lptr_t;

__device__ __forceinline__ unsigned short f2bf(float f) {
  __hip_bfloat16 h = __float2bfloat16(f);
  return *reinterpret_cast<unsigned short*>(&h);
}
__device__ __forceinline__ float bf2f(unsigned short u) {
  union { unsigned int u; float f; } x;
  x.u = ((unsigned int)u) << 16;
  return x.f;
}

// ---------------- elementwise cast f32 -> bf16 (vectorized) ----------------
__global__ void cast_bf16_k(const float* __restrict__ in, unsigned short* __restrict__ out, int n4) {
  int i = blockIdx.x * 256 + threadIdx.x;
  if (i >= n4) return;
  float4 v = ((const float4*)in)[i];
  ushort4 o;
  o.x = f2bf(v.x); o.y = f2bf(v.y); o.z = f2bf(v.z); o.w = f2bf(v.w);
  ((ushort4*)out)[i] = o;
}

// ---------------- tiled transpose-cast: in [R][C] f32 -> out [C][R] bf16 ----------------
__global__ void transpose_cast_k(const float* __restrict__ in, unsigned short* __restrict__ out,
                                 int R, int C) {
  __shared__ float tile[32][33];
  const int tc = blockIdx.x * 32, tr = blockIdx.y * 32;
  const int lx = threadIdx.x & 31, ly = threadIdx.x >> 5;
#pragma unroll
  for (int i = 0; i < 32; i += 8) tile[ly + i][lx] = in[(long)(tr + ly + i) * C + tc + lx];
  __syncthreads();
#pragma unroll
  for (int i = 0; i < 32; i += 8)
    out[(long)(tc + ly + i) * R + tr + lx] = f2bf(tile[lx][ly + i]);
}

// ---------------- V transpose (bf16): QKV cols [2560..3071] -> Vt[b*512+n][t] ----------------
__global__ void transpose_v_k(const unsigned short* __restrict__ qkv, unsigned short* __restrict__ vtp) {
  __shared__ unsigned short tile[32][33];
  const int b = blockIdx.z;
  const int t0 = blockIdx.x * 32, n0 = blockIdx.y * 32;
  const int lx = threadIdx.x & 31, ly = threadIdx.x >> 5;
#pragma unroll
  for (int i = 0; i < 32; i += 8)
    tile[ly + i][lx] = qkv[(long)(b * T_ + t0 + ly + i) * NQKV + 2560 + n0 + lx];
  __syncthreads();
#pragma unroll
  for (int i = 0; i < 32; i += 8)
    vtp[(long)(b * 512 + n0 + ly + i) * T_ + t0 + lx] = tile[lx][ly + i];
}

// ---------------- RoPE tables: cos/sin [T][64] ----------------
__global__ void rope_table_k(float* __restrict__ cosT, float* __restrict__ sinT) {
  int idx = blockIdx.x * 256 + threadIdx.x;  // t*64 + i
  int tt = idx >> 6, i = idx & 63;
  float inv = powf(10000.0f, -(float)i * (1.0f / 64.0f));
  float ang = (float)tt * inv;
  cosT[idx] = cosf(ang);
  sinT[idx] = sinf(ang);
}

// ---------------- RoPE apply in-place on QKV (Q heads get *SCALE folded in) ----------------
__global__ void rope_apply_k(unsigned short* __restrict__ qkv,
                             const float* __restrict__ cosT, const float* __restrict__ sinT) {
  int idx = blockIdx.x * 256 + threadIdx.x;  // [0, M_*20*64)
  int i = idx & 63;
  int r = idx >> 6;
  int hh = r % 20;          // 0..15 = Q heads, 16..19 = K heads
  int m = r / 20;           // row in [0, M_)
  int tt = m & (T_ - 1);
  int col = (hh < 16) ? hh * 128 + i : 2048 + (hh - 16) * 128 + i;
  float scl = (hh < 16) ? SCALE_ : 1.0f;
  unsigned short* p = qkv + (long)m * NQKV + col;
  float x0 = bf2f(p[0]), x1 = bf2f(p[64]);
  float c = cosT[tt * 64 + i], s = sinT[tt * 64 + i];
  p[0]  = f2bf((x0 * c - x1 * s) * scl);
  p[64] = f2bf((x1 * c + x0 * s) * scl);
}

// ---------------- bf16 GEMM, B transposed: C[M][N] = A[M][K] * Bt[N][K]^T ----------------
// m97 structure: 128x128 tile, 4 waves, BK=32, global_load_lds width 16.
template <bool BF16OUT>
__global__ __launch_bounds__(256) void gemm_bt(const short* __restrict__ A, const short* __restrict__ Bt,
                                               void* __restrict__ Cv, int M, int N, int K) {
  __shared__ short lA[4096];  // [128][32]
  __shared__ short lB[4096];  // [128][32]
  const int t = threadIdx.x;
  const int l = t & 63;
  const int w = t >> 6;
  const int wr = (w >> 1) * 64, wc = (w & 1) * 64;
  const int lr = l & 15, lk = (l >> 4) * 8;

  const short* Ag = A + (long)(blockIdx.x * 128 + (t >> 2)) * K + (t & 3) * 8;
  const short* Bg = Bt + (long)(blockIdx.y * 128 + (t >> 2)) * K + (t & 3) * 8;

  f32x4 acc[4][4] = {};

  for (int k0 = 0; k0 < K; k0 += 32) {
    __builtin_amdgcn_global_load_lds((gptr_t)(Ag + k0),                (lptr_t)&lA[t * 8],        16, 0, 0);
    __builtin_amdgcn_global_load_lds((gptr_t)(Ag + (long)64 * K + k0), (lptr_t)&lA[2048 + t * 8], 16, 0, 0);
    __builtin_amdgcn_global_load_lds((gptr_t)(Bg + k0),                (lptr_t)&lB[t * 8],        16, 0, 0);
    __builtin_amdgcn_global_load_lds((gptr_t)(Bg + (long)64 * K + k0), (lptr_t)&lB[2048 + t * 8], 16, 0, 0);
    __syncthreads();
    s16x8 af[4], bfr[4];
#pragma unroll
    for (int m = 0; m < 4; ++m) af[m] = *(const s16x8*)&lA[(wr + m * 16 + lr) * 32 + lk];
#pragma unroll
    for (int n = 0; n < 4; ++n) bfr[n] = *(const s16x8*)&lB[(wc + n * 16 + lr) * 32 + lk];
#pragma unroll
    for (int m = 0; m < 4; ++m)
#pragma unroll
      for (int n = 0; n < 4; ++n)
        acc[m][n] = __builtin_amdgcn_mfma_f32_16x16x32_bf16(af[m], bfr[n], acc[m][n], 0, 0, 0);
    __syncthreads();
  }

#pragma unroll
  for (int m = 0; m < 4; ++m) {
    const int row0 = blockIdx.x * 128 + wr + m * 16 + (l >> 4) * 4;
#pragma unroll
    for (int n = 0; n < 4; ++n) {
      const int col = blockIdx.y * 128 + wc + n * 16 + lr;
#pragma unroll
      for (int r = 0; r < 4; ++r) {
        float v = acc[m][n][r];
        if constexpr (BF16OUT)
          ((unsigned short*)Cv)[(long)(row0 + r) * N + col] = f2bf(v);
        else
          ((float*)Cv)[(long)(row0 + r) * N + col] = v;
      }
    }
  }
}

// ---------------- causal GQA flash attention v2 ----------------
// Pair-balanced: block (pj, bh) processes q-tiles {pj, 31-pj} -> uniform 33 kv-tiles/block.
// Grid (16, 32) = 512 blocks x 4 waves. K staged in LDS (shared by all waves),
// double-buffered global_load_lds w=16, XOR-swizzled (row&7)<<4 per rule #21
// (linear LDS dest + inverse-swizzled global source + swizzled ds_read).
// V read direct from L2-resident Vt (m169 lesson; also balances LDS vs L2 pipes).
__global__ __launch_bounds__(256) void attn_kernel(const short* __restrict__ qkv,
                                                   const short* __restrict__ vt,
                                                   unsigned short* __restrict__ outp) {
  const int pj = blockIdx.x;       // 0..15
  const int bh = blockIdx.y;       // 0..31
  const int b = bh >> 4, h = bh & 15, hkv = h >> 2;
  const int tid = threadIdx.x, w = tid >> 6, l = tid & 63;
  const int lr = l & 15, lg = l >> 4;

  __shared__ short lK[2][8192];     // [2][64 rows][128 cols] bf16, swizzled
  __shared__ short lP[4][16 * 72];  // per-wave P tile [16 q][64 kv], padded ld=72

  const short* kb = qkv + (long)(b * T_) * NQKV + 2048 + hkv * HD_;
  const short* vb = vt + (long)(b * 512 + hkv * HD_) * T_;
  short* pw = &lP[w][0];

  auto STAGE = [&](int buf, int kvt) {
#pragma unroll
    for (int i = 0; i < 4; ++i) {
      int flat16 = i * 256 + tid;           // 16B-chunk id 0..1023
      int r = flat16 >> 4;                  // kv row 0..63
      int cb = (flat16 & 15) << 4;          // linear col byte
      int scb = cb ^ ((r & 7) << 4);        // inverse-swizzled source col byte
      const short* src = kb + (long)(kvt * 64 + r) * NQKV + (scb >> 1);
      __builtin_amdgcn_global_load_lds((gptr_t)src, (lptr_t)&lK[buf][flat16 * 8], 16, 0, 0);
    }
  };

#pragma unroll 1
  for (int ph = 0; ph < 2; ++ph) {
    const int qtile = ph ? 31 - pj : pj;
    const int ntiles = qtile + 1;

    // Q fragments (A operand): row = lr, k contiguous. SCALE folded in by RoPE.
    const short* qp = qkv + (long)(b * T_ + qtile * 64 + w * 16 + lr) * NQKV + h * HD_;
    s16x8 qf[4];
#pragma unroll
    for (int ks = 0; ks < 4; ++ks) qf[ks] = *(const s16x8*)(qp + ks * 32 + lg * 8);

    f32x4 o[8] = {};
    float mrun[4], lrun[4];
#pragma unroll
    for (int r = 0; r < 4; ++r) { mrun[r] = -1e30f; lrun[r] = 0.f; }

    STAGE(0, 0);
    __syncthreads();
    int cur = 0;

    for (int kvt = 0; kvt < ntiles; ++kvt) {
      if (kvt + 1 < ntiles) STAGE(cur ^ 1, kvt + 1);

      // ---- S = Q K^T from LDS (swizzled reads) ----
      const char* lkb = (const char*)&lK[cur][0];
      f32x4 s[4] = {};
#pragma unroll
      for (int nb = 0; nb < 4; ++nb) {
        const int row = nb * 16 + lr;
        const int rb = row * 256;
        const int xr = (row & 7) << 4;
#pragma unroll
        for (int ks = 0; ks < 4; ++ks) {
          s16x8 kf = *(const s16x8*)(lkb + (rb + ((ks * 64 + lg * 16) ^ xr)));
          s[nb] = __builtin_amdgcn_mfma_f32_16x16x32_bf16(qf[ks], kf, s[nb], 0, 0, 0);
        }
      }
      // ---- causal mask on the diagonal tile ----
      if (kvt == qtile) {
#pragma unroll
        for (int nb = 0; nb < 4; ++nb)
#pragma unroll
          for (int r = 0; r < 4; ++r)
            if (nb * 16 + lr > w * 16 + lg * 4 + r) s[nb][r] = -1e30f;
      }
      // ---- online softmax (rows live in 16-lane groups) ----
      float sc[4];
#pragma unroll
      for (int r = 0; r < 4; ++r) {
        float v = fmaxf(fmaxf(s[0][r], s[1][r]), fmaxf(s[2][r], s[3][r]));
        v = fmaxf(v, __shfl_xor(v, 1));
        v = fmaxf(v, __shfl_xor(v, 2));
        v = fmaxf(v, __shfl_xor(v, 4));
        v = fmaxf(v, __shfl_xor(v, 8));
        float mnew = fmaxf(mrun[r], v);
        sc[r] = __expf(mrun[r] - mnew);
        mrun[r] = mnew;
      }
      float ps[4] = {0.f, 0.f, 0.f, 0.f};
#pragma unroll
      for (int nb = 0; nb < 4; ++nb)
#pragma unroll
        for (int r = 0; r < 4; ++r) {
          float p = __expf(s[nb][r] - mrun[r]);
          s[nb][r] = p;
          ps[r] += p;
        }
#pragma unroll
      for (int r = 0; r < 4; ++r) {
        ps[r] += __shfl_xor(ps[r], 1);
        ps[r] += __shfl_xor(ps[r], 2);
        ps[r] += __shfl_xor(ps[r], 4);
        ps[r] += __shfl_xor(ps[r], 8);
        lrun[r] = lrun[r] * sc[r] + ps[r];
      }
#pragma unroll
      for (int db = 0; db < 8; ++db)
#pragma unroll
        for (int r = 0; r < 4; ++r) o[db][r] *= sc[r];
      // ---- P -> LDS (bf16), C-layout rows -> A-layout rows ----
#pragma unroll
      for (int nb = 0; nb < 4; ++nb)
#pragma unroll
        for (int r = 0; r < 4; ++r)
          pw[(lg * 4 + r) * 72 + nb * 16 + lr] = (short)f2bf(s[nb][r]);
      // ---- O += P V  (B operand from pre-transposed Vt, direct from L2) ----
#pragma unroll
      for (int ks2 = 0; ks2 < 2; ++ks2) {
        s16x8 pf = *(const s16x8*)&pw[lr * 72 + ks2 * 32 + lg * 8];
#pragma unroll
        for (int db = 0; db < 8; ++db) {
          s16x8 vf = *(const s16x8*)(vb + (long)(db * 16 + lr) * T_ + kvt * 64 + ks2 * 32 + lg * 8);
          o[db] = __builtin_amdgcn_mfma_f32_16x16x32_bf16(pf, vf, o[db], 0, 0, 0);
        }
      }
      __syncthreads();   // drains vmcnt (next-tile stage done) + guards buffer reuse
      cur ^= 1;
    }

    // ---- normalize and store (bf16) ----
    unsigned short* ob = outp + (long)(b * T_ + qtile * 64 + w * 16) * HID_ + h * HD_;
#pragma unroll
    for (int db = 0; db < 8; ++db)
#pragma unroll
      for (int r = 0; r < 4; ++r)
        ob[(long)(lg * 4 + r) * HID_ + db * 16 + lr] = f2bf(o[db][r] / lrun[r]);
  }
}

// ---------------- launch ----------------
extern "C" void kernel_launch(void* const* d_in, const int* in_sizes, int n_in,
                              void* d_out, int out_size, void* d_ws, size_t ws_size,
                              hipStream_t stream) {
  (void)in_sizes; (void)n_in; (void)out_size; (void)ws_size;
  const float* x  = (const float*)d_in[0];
  const float* Wq = (const float*)d_in[1];
  const float* Wk = (const float*)d_in[2];
  const float* Wv = (const float*)d_in[3];
  const float* Wo = (const float*)d_in[4];
  float* outp = (float*)d_out;

  char* wsp = (char*)d_ws;
  auto take = [&](size_t bytes) { char* p = wsp; wsp += (bytes + 255) & ~(size_t)255; return p; };
  unsigned short* xb    = (unsigned short*)take((size_t)M_ * HID_ * 2);    // x in bf16
  unsigned short* WqkvT = (unsigned short*)take((size_t)NQKV * HID_ * 2);  // [3072][2048] W^T bf16
  unsigned short* WoT   = (unsigned short*)take((size_t)HID_ * HID_ * 2);  // [2048][2048]
  unsigned short* QKV   = (unsigned short*)take((size_t)M_ * NQKV * 2);    // [4096][3072]
  unsigned short* Vtb   = (unsigned short*)take((size_t)1024 * T_ * 2);    // [b*512+n][T]
  unsigned short* AO    = (unsigned short*)take((size_t)M_ * HID_ * 2);    // attention out bf16
  float* cosT = (float*)take((size_t)T_ * 64 * 4);
  float* sinT = (float*)take((size_t)T_ * 64 * 4);

  cast_bf16_k<<<8192, 256, 0, stream>>>(x, xb, M_ * HID_ / 4);
  transpose_cast_k<<<dim3(64, 64), 256, 0, stream>>>(Wq, WqkvT, 2048, 2048);
  transpose_cast_k<<<dim3(16, 64), 256, 0, stream>>>(Wk, WqkvT + (size_t)2048 * 2048, 2048, 512);
  transpose_cast_k<<<dim3(16, 64), 256, 0, stream>>>(Wv, WqkvT + (size_t)2560 * 2048, 2048, 512);
  transpose_cast_k<<<dim3(64, 64), 256, 0, stream>>>(Wo, WoT, 2048, 2048);
  rope_table_k<<<512, 256, 0, stream>>>(cosT, sinT);

  // QKV = xb @ WqkvT^T   (M=4096, N=3072, K=2048), bf16 out
  gemm_bt<true><<<dim3(32, 24), 256, 0, stream>>>((const short*)xb, (const short*)WqkvT,
                                                  (void*)QKV, M_, NQKV, HID_);
  rope_apply_k<<<(M_ * 20 * 64) / 256, 256, 0, stream>>>(QKV, cosT, sinT);
  transpose_v_k<<<dim3(64, 16, 2), 256, 0, stream>>>(QKV, Vtb);

  attn_kernel<<<dim3(16, 32), 256, 0, stream>>>((const short*)QKV, (const short*)Vtb, AO);

  // out = AO @ WoT^T   (M=4096, N=2048, K=2048), f32 out
  gemm_bt<false><<<dim3(32, 16), 256, 0, stream>>>((const short*)AO, (const short*)WoT,
                                                   (void*)outp, M_, HID_, HID_);
}

// Round 7
// 398.732 us; speedup vs baseline: 2.0095x; 1.0276x over previous
//
#include <hip/hip_runtime.h>
#include <hip/hip_bf16.h>

// Problem constants (GroupedQueryAttention): B=2, T=2048, HID=2048, H=16, HKV=4, HD=128
#define B_   2
#define T_   2048
#define HID_ 2048
#define H_   16
#define HKV_ 4
#define HD_  128
#define NQKV 3072   // H*HD + 2*HKV*HD = 2048 + 512 + 512
#define M_   4096   // B*T
#define SCALE_ 0.08838834764831845f  // 128^-0.5

using f32x4 = __attribute__((ext_vector_type(4))) float;
using s16x8 = __attribute__((ext_vector_type(8))) short;
using u16x8 = __attribute__((ext_vector_type(8))) unsigned short;

typedef const __attribute__((address_space(1))) unsigned int* gptr_t;
typedef __attribute__((address_space(3))) unsigned int* lptr_t;

__device__ __forceinline__ unsigned short f2bf(float f) {
  __hip_bfloat16 h = __float2bfloat16(f);
  return *reinterpret_cast<unsigned short*>(&h);
}
__device__ __forceinline__ float bf2f(unsigned short u) {
  union { unsigned int u; float f; } x;
  x.u = ((unsigned int)u) << 16;
  return x.f;
}

// ---------------- elementwise cast f32 -> bf16 (16B stores) ----------------
__global__ void cast_bf16_k(const float* __restrict__ in, unsigned short* __restrict__ out, int n8) {
  int i = blockIdx.x * 256 + threadIdx.x;
  if (i >= n8) return;
  float4 v0 = ((const float4*)in)[i * 2];
  float4 v1 = ((const float4*)in)[i * 2 + 1];
  u16x8 o;
  o[0] = f2bf(v0.x); o[1] = f2bf(v0.y); o[2] = f2bf(v0.z); o[3] = f2bf(v0.w);
  o[4] = f2bf(v1.x); o[5] = f2bf(v1.y); o[6] = f2bf(v1.z); o[7] = f2bf(v1.w);
  ((u16x8*)out)[i] = o;
}

// ---------------- tiled transpose-cast: in [R][C] f32 -> out [C][R] bf16 ----------------
__global__ void transpose_cast_k(const float* __restrict__ in, unsigned short* __restrict__ out,
                                 int R, int C) {
  __shared__ float tile[32][33];
  const int tc = blockIdx.x * 32, tr = blockIdx.y * 32;
  const int lx = threadIdx.x & 31, ly = threadIdx.x >> 5;
#pragma unroll
  for (int i = 0; i < 32; i += 8) tile[ly + i][lx] = in[(long)(tr + ly + i) * C + tc + lx];
  __syncthreads();
#pragma unroll
  for (int i = 0; i < 32; i += 8)
    out[(long)(tc + ly + i) * R + tr + lx] = f2bf(tile[lx][ly + i]);
}

// ---------------- V transpose (bf16): QKV cols [2560..3071] -> Vt[b*512+n][t] ----------------
__global__ void transpose_v_k(const unsigned short* __restrict__ qkv, unsigned short* __restrict__ vtp) {
  __shared__ unsigned short tile[32][33];
  const int b = blockIdx.z;
  const int t0 = blockIdx.x * 32, n0 = blockIdx.y * 32;
  const int lx = threadIdx.x & 31, ly = threadIdx.x >> 5;
#pragma unroll
  for (int i = 0; i < 32; i += 8)
    tile[ly + i][lx] = qkv[(long)(b * T_ + t0 + ly + i) * NQKV + 2560 + n0 + lx];
  __syncthreads();
#pragma unroll
  for (int i = 0; i < 32; i += 8)
    vtp[(long)(b * 512 + n0 + ly + i) * T_ + t0 + lx] = tile[lx][ly + i];
}

// ---------------- RoPE tables: cos/sin [T][64] ----------------
__global__ void rope_table_k(float* __restrict__ cosT, float* __restrict__ sinT) {
  int idx = blockIdx.x * 256 + threadIdx.x;  // t*64 + i
  int tt = idx >> 6, i = idx & 63;
  float inv = powf(10000.0f, -(float)i * (1.0f / 64.0f));
  float ang = (float)tt * inv;
  cosT[idx] = cosf(ang);
  sinT[idx] = sinf(ang);
}

// ---------------- RoPE apply, vectorized: 8 (i, i+64) pairs per thread ----------------
__global__ void rope_apply_k(unsigned short* __restrict__ qkv,
                             const float* __restrict__ cosT, const float* __restrict__ sinT) {
  int idx = blockIdx.x * 256 + threadIdx.x;  // [0, M_*20*8)
  int g = idx & 7;          // 8-wide group within half-head
  int r = idx >> 3;
  int hh = r % 20;          // 0..15 = Q heads, 16..19 = K heads
  int m = r / 20;           // row in [0, M_)
  int tt = m & (T_ - 1);
  int col = ((hh < 16) ? hh * 128 : 2048 + (hh - 16) * 128) + g * 8;
  float scl = (hh < 16) ? SCALE_ : 1.0f;
  unsigned short* p = qkv + (long)m * NQKV + col;
  u16x8 lo = *(const u16x8*)(p);
  u16x8 hi = *(const u16x8*)(p + 64);
  const float4* cp = (const float4*)(cosT + tt * 64 + g * 8);
  const float4* sp = (const float4*)(sinT + tt * 64 + g * 8);
  float c[8], s[8];
  { float4 a = cp[0], b = cp[1]; c[0]=a.x;c[1]=a.y;c[2]=a.z;c[3]=a.w;c[4]=b.x;c[5]=b.y;c[6]=b.z;c[7]=b.w; }
  { float4 a = sp[0], b = sp[1]; s[0]=a.x;s[1]=a.y;s[2]=a.z;s[3]=a.w;s[4]=b.x;s[5]=b.y;s[6]=b.z;s[7]=b.w; }
  u16x8 olo, ohi;
#pragma unroll
  for (int j = 0; j < 8; ++j) {
    float x0 = bf2f(lo[j]), x1 = bf2f(hi[j]);
    olo[j] = f2bf((x0 * c[j] - x1 * s[j]) * scl);
    ohi[j] = f2bf((x1 * c[j] + x0 * s[j]) * scl);
  }
  *(u16x8*)(p) = olo;
  *(u16x8*)(p + 64) = ohi;
}

// ---------------- bf16 GEMM, B transposed: C[M][N] = A[M][K] * Bt[N][K]^T ----------------
// m97 structure: 128x128 tile, 4 waves, BK=32, global_load_lds width 16.
template <bool BF16OUT>
__global__ __launch_bounds__(256) void gemm_bt(const short* __restrict__ A, const short* __restrict__ Bt,
                                               void* __restrict__ Cv, int M, int N, int K) {
  __shared__ short lA[4096];  // [128][32]
  __shared__ short lB[4096];  // [128][32]
  const int t = threadIdx.x;
  const int l = t & 63;
  const int w = t >> 6;
  const int wr = (w >> 1) * 64, wc = (w & 1) * 64;
  const int lr = l & 15, lk = (l >> 4) * 8;

  const short* Ag = A + (long)(blockIdx.x * 128 + (t >> 2)) * K + (t & 3) * 8;
  const short* Bg = Bt + (long)(blockIdx.y * 128 + (t >> 2)) * K + (t & 3) * 8;

  f32x4 acc[4][4] = {};

  for (int k0 = 0; k0 < K; k0 += 32) {
    __builtin_amdgcn_global_load_lds((gptr_t)(Ag + k0),                (lptr_t)&lA[t * 8],        16, 0, 0);
    __builtin_amdgcn_global_load_lds((gptr_t)(Ag + (long)64 * K + k0), (lptr_t)&lA[2048 + t * 8], 16, 0, 0);
    __builtin_amdgcn_global_load_lds((gptr_t)(Bg + k0),                (lptr_t)&lB[t * 8],        16, 0, 0);
    __builtin_amdgcn_global_load_lds((gptr_t)(Bg + (long)64 * K + k0), (lptr_t)&lB[2048 + t * 8], 16, 0, 0);
    __syncthreads();
    s16x8 af[4], bfr[4];
#pragma unroll
    for (int m = 0; m < 4; ++m) af[m] = *(const s16x8*)&lA[(wr + m * 16 + lr) * 32 + lk];
#pragma unroll
    for (int n = 0; n < 4; ++n) bfr[n] = *(const s16x8*)&lB[(wc + n * 16 + lr) * 32 + lk];
#pragma unroll
    for (int m = 0; m < 4; ++m)
#pragma unroll
      for (int n = 0; n < 4; ++n)
        acc[m][n] = __builtin_amdgcn_mfma_f32_16x16x32_bf16(af[m], bfr[n], acc[m][n], 0, 0, 0);
    __syncthreads();
  }

#pragma unroll
  for (int m = 0; m < 4; ++m) {
    const int row0 = blockIdx.x * 128 + wr + m * 16 + (l >> 4) * 4;
#pragma unroll
    for (int n = 0; n < 4; ++n) {
      const int col = blockIdx.y * 128 + wc + n * 16 + lr;
#pragma unroll
      for (int r = 0; r < 4; ++r) {
        float v = acc[m][n][r];
        if constexpr (BF16OUT)
          ((unsigned short*)Cv)[(long)(row0 + r) * N + col] = f2bf(v);
        else
          ((float*)Cv)[(long)(row0 + r) * N + col] = v;
      }
    }
  }
}

// ---------------- causal GQA flash attention v3 ----------------
// v2 + V-register prefetch: all 16 V fragments for the CURRENT tile are loaded
// into registers at the tile top, so their ~200-400cy L2 latency hides under
// QK^T + softmax (~1500cy). +64 VGPR (~190 total), __launch_bounds__(256,2)
// keeps 2 waves/SIMD.
__global__ __launch_bounds__(256, 2) void attn_kernel(const short* __restrict__ qkv,
                                                      const short* __restrict__ vt,
                                                      unsigned short* __restrict__ outp) {
  const int pj = blockIdx.x;       // 0..15
  const int bh = blockIdx.y;       // 0..31
  const int b = bh >> 4, h = bh & 15, hkv = h >> 2;
  const int tid = threadIdx.x, w = tid >> 6, l = tid & 63;
  const int lr = l & 15, lg = l >> 4;

  __shared__ short lK[2][8192];     // [2][64 rows][128 cols] bf16, swizzled
  __shared__ short lP[4][16 * 72];  // per-wave P tile [16 q][64 kv], padded ld=72

  const short* kb = qkv + (long)(b * T_) * NQKV + 2048 + hkv * HD_;
  const short* vb = vt + (long)(b * 512 + hkv * HD_) * T_;
  short* pw = &lP[w][0];

  auto STAGE = [&](int buf, int kvt) {
#pragma unroll
    for (int i = 0; i < 4; ++i) {
      int flat16 = i * 256 + tid;           // 16B-chunk id 0..1023
      int r = flat16 >> 4;                  // kv row 0..63
      int cb = (flat16 & 15) << 4;          // linear col byte
      int scb = cb ^ ((r & 7) << 4);        // inverse-swizzled source col byte
      const short* src = kb + (long)(kvt * 64 + r) * NQKV + (scb >> 1);
      __builtin_amdgcn_global_load_lds((gptr_t)src, (lptr_t)&lK[buf][flat16 * 8], 16, 0, 0);
    }
  };

#pragma unroll 1
  for (int ph = 0; ph < 2; ++ph) {
    const int qtile = ph ? 31 - pj : pj;
    const int ntiles = qtile + 1;

    // Q fragments (A operand): row = lr, k contiguous. SCALE folded in by RoPE.
    const short* qp = qkv + (long)(b * T_ + qtile * 64 + w * 16 + lr) * NQKV + h * HD_;
    s16x8 qf[4];
#pragma unroll
    for (int ks = 0; ks < 4; ++ks) qf[ks] = *(const s16x8*)(qp + ks * 32 + lg * 8);

    f32x4 o[8] = {};
    float mrun[4], lrun[4];
#pragma unroll
    for (int r = 0; r < 4; ++r) { mrun[r] = -1e30f; lrun[r] = 0.f; }

    STAGE(0, 0);
    __syncthreads();
    int cur = 0;

    for (int kvt = 0; kvt < ntiles; ++kvt) {
      if (kvt + 1 < ntiles) STAGE(cur ^ 1, kvt + 1);

      // ---- V prefetch for THIS tile into registers (latency hides under QK+softmax) ----
      s16x8 vf[2][8];
#pragma unroll
      for (int ks2 = 0; ks2 < 2; ++ks2)
#pragma unroll
        for (int db = 0; db < 8; ++db)
          vf[ks2][db] = *(const s16x8*)(vb + (long)(db * 16 + lr) * T_ + kvt * 64 + ks2 * 32 + lg * 8);

      // ---- S = Q K^T from LDS (swizzled reads) ----
      const char* lkb = (const char*)&lK[cur][0];
      f32x4 s[4] = {};
#pragma unroll
      for (int nb = 0; nb < 4; ++nb) {
        const int row = nb * 16 + lr;
        const int rb = row * 256;
        const int xr = (row & 7) << 4;
#pragma unroll
        for (int ks = 0; ks < 4; ++ks) {
          s16x8 kf = *(const s16x8*)(lkb + (rb + ((ks * 64 + lg * 16) ^ xr)));
          s[nb] = __builtin_amdgcn_mfma_f32_16x16x32_bf16(qf[ks], kf, s[nb], 0, 0, 0);
        }
      }
      // ---- causal mask on the diagonal tile ----
      if (kvt == qtile) {
#pragma unroll
        for (int nb = 0; nb < 4; ++nb)
#pragma unroll
          for (int r = 0; r < 4; ++r)
            if (nb * 16 + lr > w * 16 + lg * 4 + r) s[nb][r] = -1e30f;
      }
      // ---- online softmax (rows live in 16-lane groups) ----
      float sc[4];
#pragma unroll
      for (int r = 0; r < 4; ++r) {
        float v = fmaxf(fmaxf(s[0][r], s[1][r]), fmaxf(s[2][r], s[3][r]));
        v = fmaxf(v, __shfl_xor(v, 1));
        v = fmaxf(v, __shfl_xor(v, 2));
        v = fmaxf(v, __shfl_xor(v, 4));
        v = fmaxf(v, __shfl_xor(v, 8));
        float mnew = fmaxf(mrun[r], v);
        sc[r] = __expf(mrun[r] - mnew);
        mrun[r] = mnew;
      }
      float ps[4] = {0.f, 0.f, 0.f, 0.f};
#pragma unroll
      for (int nb = 0; nb < 4; ++nb)
#pragma unroll
        for (int r = 0; r < 4; ++r) {
          float p = __expf(s[nb][r] - mrun[r]);
          s[nb][r] = p;
          ps[r] += p;
        }
#pragma unroll
      for (int r = 0; r < 4; ++r) {
        ps[r] += __shfl_xor(ps[r], 1);
        ps[r] += __shfl_xor(ps[r], 2);
        ps[r] += __shfl_xor(ps[r], 4);
        ps[r] += __shfl_xor(ps[r], 8);
        lrun[r] = lrun[r] * sc[r] + ps[r];
      }
#pragma unroll
      for (int db = 0; db < 8; ++db)
#pragma unroll
        for (int r = 0; r < 4; ++r) o[db][r] *= sc[r];
      // ---- P -> LDS (bf16), C-layout rows -> A-layout rows ----
#pragma unroll
      for (int nb = 0; nb < 4; ++nb)
#pragma unroll
        for (int r = 0; r < 4; ++r)
          pw[(lg * 4 + r) * 72 + nb * 16 + lr] = (short)f2bf(s[nb][r]);
      // ---- O += P V  (V already in registers) ----
#pragma unroll
      for (int ks2 = 0; ks2 < 2; ++ks2) {
        s16x8 pf = *(const s16x8*)&pw[lr * 72 + ks2 * 32 + lg * 8];
#pragma unroll
        for (int db = 0; db < 8; ++db)
          o[db] = __builtin_amdgcn_mfma_f32_16x16x32_bf16(pf, vf[ks2][db], o[db], 0, 0, 0);
      }
      __syncthreads();   // drains vmcnt (next-tile stage done) + guards buffer reuse
      cur ^= 1;
    }

    // ---- normalize and store (bf16) ----
    unsigned short* ob = outp + (long)(b * T_ + qtile * 64 + w * 16) * HID_ + h * HD_;
#pragma unroll
    for (int db = 0; db < 8; ++db)
#pragma unroll
      for (int r = 0; r < 4; ++r)
        ob[(long)(lg * 4 + r) * HID_ + db * 16 + lr] = f2bf(o[db][r] / lrun[r]);
  }
}

// ---------------- launch ----------------
extern "C" void kernel_launch(void* const* d_in, const int* in_sizes, int n_in,
                              void* d_out, int out_size, void* d_ws, size_t ws_size,
                              hipStream_t stream) {
  (void)in_sizes; (void)n_in; (void)out_size; (void)ws_size;
  const float* x  = (const float*)d_in[0];
  const float* Wq = (const float*)d_in[1];
  const float* Wk = (const float*)d_in[2];
  const float* Wv = (const float*)d_in[3];
  const float* Wo = (const float*)d_in[4];
  float* outp = (float*)d_out;

  char* wsp = (char*)d_ws;
  auto take = [&](size_t bytes) { char* p = wsp; wsp += (bytes + 255) & ~(size_t)255; return p; };
  unsigned short* xb    = (unsigned short*)take((size_t)M_ * HID_ * 2);    // x in bf16
  unsigned short* WqkvT = (unsigned short*)take((size_t)NQKV * HID_ * 2);  // [3072][2048] W^T bf16
  unsigned short* WoT   = (unsigned short*)take((size_t)HID_ * HID_ * 2);  // [2048][2048]
  unsigned short* QKV   = (unsigned short*)take((size_t)M_ * NQKV * 2);    // [4096][3072]
  unsigned short* Vtb   = (unsigned short*)take((size_t)1024 * T_ * 2);    // [b*512+n][T]
  unsigned short* AO    = (unsigned short*)take((size_t)M_ * HID_ * 2);    // attention out bf16
  float* cosT = (float*)take((size_t)T_ * 64 * 4);
  float* sinT = (float*)take((size_t)T_ * 64 * 4);

  cast_bf16_k<<<4096, 256, 0, stream>>>(x, xb, M_ * HID_ / 8);
  transpose_cast_k<<<dim3(64, 64), 256, 0, stream>>>(Wq, WqkvT, 2048, 2048);
  transpose_cast_k<<<dim3(16, 64), 256, 0, stream>>>(Wk, WqkvT + (size_t)2048 * 2048, 2048, 512);
  transpose_cast_k<<<dim3(16, 64), 256, 0, stream>>>(Wv, WqkvT + (size_t)2560 * 2048, 2048, 512);
  transpose_cast_k<<<dim3(64, 64), 256, 0, stream>>>(Wo, WoT, 2048, 2048);
  rope_table_k<<<512, 256, 0, stream>>>(cosT, sinT);

  // QKV = xb @ WqkvT^T   (M=4096, N=3072, K=2048), bf16 out
  gemm_bt<true><<<dim3(32, 24), 256, 0, stream>>>((const short*)xb, (const short*)WqkvT,
                                                  (void*)QKV, M_, NQKV, HID_);
  rope_apply_k<<<(M_ * 20 * 8) / 256, 256, 0, stream>>>(QKV, cosT, sinT);
  transpose_v_k<<<dim3(64, 16, 2), 256, 0, stream>>>(QKV, Vtb);

  attn_kernel<<<dim3(16, 32), 256, 0, stream>>>((const short*)QKV, (const short*)Vtb, AO);

  // out = AO @ WoT^T   (M=4096, N=2048, K=2048), f32 out
  gemm_bt<false><<<dim3(32, 16), 256, 0, stream>>>((const short*)AO, (const short*)WoT,
                                                   (void*)outp, M_, HID_, HID_);
}